// Round 16
// baseline (57.848 us; speedup 1.0000x reference)
//
#include <hip/hip_runtime.h>
#include <cstdint>

#define NN 4096
#define FF 512

typedef short bf16x8 __attribute__((ext_vector_type(8)));
typedef float f32x4 __attribute__((ext_vector_type(4)));
typedef float f32x16 __attribute__((ext_vector_type(16)));

__device__ __forceinline__ uint16_t f2bf(float f) {
    uint32_t u = __builtin_bit_cast(uint32_t, f);
    u += 0x7FFFu + ((u >> 16) & 1u);   // round-to-nearest-even
    return (uint16_t)(u >> 16);
}
__device__ __forceinline__ float bf2f(uint32_t h) {
    uint32_t u = h << 16;
    return __builtin_bit_cast(float, u);
}

// ---------------------------------------------------------------------------
// k_pre: fused preprocessing, one launch (R14-verified).
//   blocks [0,1024):    prep — Abf[i][j]=bf16(adj+I), d_i=rsqrt(1+rowsum)
//   blocks [1024,3072): xc   — x f32 -> bf16
//   blocks [3072,3328): wc   — W f32 -> bf16
// ---------------------------------------------------------------------------
__global__ __launch_bounds__(256) void k_pre(const float* __restrict__ adj,
                                             const float* __restrict__ x,
                                             const float* __restrict__ W,
                                             float* __restrict__ d,
                                             uint16_t* __restrict__ Abf,
                                             uint16_t* __restrict__ xbf,
                                             uint16_t* __restrict__ Wbf) {
    const int bid = blockIdx.x;
    if (bid < 1024) {
        const int row  = bid * 4 + (threadIdx.x >> 6);
        const int lane = threadIdx.x & 63;
        const float4* p = (const float4*)(adj + (size_t)row * NN);
        float4 v[16];
        float s = 0.f;
#pragma unroll
        for (int i = 0; i < 16; ++i) {
            v[i] = p[lane + i * 64];
            s += (v[i].x + v[i].y) + (v[i].z + v[i].w);
        }
#pragma unroll
        for (int off = 1; off < 64; off <<= 1) s += __shfl_xor(s, off);
        const float di = rsqrtf(s + 1.0f);
        if (lane == 0) d[row] = di;
        uint16_t* outp = Abf + (size_t)row * NN;
#pragma unroll
        for (int i = 0; i < 16; ++i) {
            const int cb = (lane + i * 64) * 4;
            float a0 = v[i].x, a1 = v[i].y, a2 = v[i].z, a3 = v[i].w;
            if (cb + 0 == row) a0 += 1.0f;
            if (cb + 1 == row) a1 += 1.0f;
            if (cb + 2 == row) a2 += 1.0f;
            if (cb + 3 == row) a3 += 1.0f;
            ushort4 o;
            o.x = f2bf(a0); o.y = f2bf(a1); o.z = f2bf(a2); o.w = f2bf(a3);
            *(ushort4*)(outp + cb) = o;
        }
    } else if (bid < 3072) {
        const size_t t4 = (size_t)(bid - 1024) * 256 + threadIdx.x;
        float4 v = *(const float4*)(x + t4 * 4);
        ushort4 o;
        o.x = f2bf(v.x); o.y = f2bf(v.y); o.z = f2bf(v.z); o.w = f2bf(v.w);
        *(ushort4*)(xbf + t4 * 4) = o;
    } else {
        const size_t t4 = (size_t)(bid - 3072) * 256 + threadIdx.x;
        float4 v = *(const float4*)(W + t4 * 4);
        ushort4 o;
        o.x = f2bf(v.x); o.y = f2bf(v.y); o.z = f2bf(v.z); o.w = f2bf(v.w);
        *(ushort4*)(Wbf + t4 * 4) = o;
    }
}

// ---------------------------------------------------------------------------
// k_mmz: fused small GEMM + transpose + d-scale (R12-R14 verified).
// zdT[n][k] = bf16( d[k] * (x @ W^T)[k][n] )
// ---------------------------------------------------------------------------
__global__ __launch_bounds__(256, 4) void k_mmz(const uint16_t* __restrict__ A,
                                                const uint16_t* __restrict__ Bt,
                                                const float* __restrict__ d,
                                                uint16_t* __restrict__ zdT) {
    constexpr int BM = 64, BN = 64, K = FF;
    constexpr int NTC = FF / BN;          // 8
    constexpr int NT  = K / 64;           // 8

    __shared__ uint16_t As[BM * 64];
    __shared__ uint16_t Bs[BN * 64];
    __shared__ uint16_t tt[64][80];

    const int id = blockIdx.x;
    const int mt = id / NTC;
    const int nt = id % NTC;
    const int m0 = mt * BM;
    const int n0 = nt * BN;

    const int tid  = threadIdx.x;
    const int w    = tid >> 6;
    const int lane = tid & 63;
    const int wm = w >> 1, wn = w & 1;

    f32x4 acc[2][2] = {};

    for (int t = 0; t < NT; ++t) {
        const int ktb = t * 64;
#pragma unroll
        for (int i = 0; i < 2; ++i) {
            const int boff = i * 4096 + tid * 16;
            const int row  = boff >> 7;
            const int q    = (boff >> 4) & 7;
            const int c    = q ^ (row & 7);
            const uint16_t* src = A + (size_t)(m0 + row) * K + ktb + c * 8;
            __builtin_amdgcn_global_load_lds(
                (const __attribute__((address_space(1))) void*)src,
                (__attribute__((address_space(3))) void*)&As[boff >> 1],
                16, 0, 0);
        }
#pragma unroll
        for (int i = 0; i < 2; ++i) {
            const int boff = i * 4096 + tid * 16;
            const int row  = boff >> 7;
            const int q    = (boff >> 4) & 7;
            const int c    = q ^ (row & 7);
            const uint16_t* src = Bt + (size_t)(n0 + row) * K + ktb + c * 8;
            __builtin_amdgcn_global_load_lds(
                (const __attribute__((address_space(1))) void*)src,
                (__attribute__((address_space(3))) void*)&Bs[boff >> 1],
                16, 0, 0);
        }
        __syncthreads();
#pragma unroll
        for (int kk = 0; kk < 2; ++kk) {
            const int cl = kk * 4 + (lane >> 4);
            bf16x8 af[2], bfr[2];
#pragma unroll
            for (int mf = 0; mf < 2; ++mf) {
                const int r = wm * 32 + mf * 16 + (lane & 15);
                af[mf] = *(const bf16x8*)&As[r * 64 + ((cl ^ (r & 7)) << 3)];
            }
#pragma unroll
            for (int nf = 0; nf < 2; ++nf) {
                const int r = wn * 32 + nf * 16 + (lane & 15);
                bfr[nf] = *(const bf16x8*)&Bs[r * 64 + ((cl ^ (r & 7)) << 3)];
            }
#pragma unroll
            for (int mf = 0; mf < 2; ++mf)
#pragma unroll
                for (int nf = 0; nf < 2; ++nf)
                    acc[mf][nf] = __builtin_amdgcn_mfma_f32_16x16x32_bf16(
                        af[mf], bfr[nf], acc[mf][nf], 0, 0, 0);
        }
        __syncthreads();
    }

    const int rb = wm * 32 + ((lane >> 4) << 2);
    const int cb = wn * 32 + (lane & 15);
#pragma unroll
    for (int mf = 0; mf < 2; ++mf)
#pragma unroll
        for (int nf = 0; nf < 2; ++nf) {
            const int col_l = cb + nf * 16;
#pragma unroll
            for (int r = 0; r < 4; ++r) {
                const int row_l = rb + mf * 16 + r;
                tt[col_l][row_l] = f2bf(acc[mf][nf][r] * d[m0 + row_l]);
            }
        }
    __syncthreads();
    const int n_l = tid >> 2;
    const int ch  = tid & 3;
    uint4* dst = (uint4*)(zdT + (size_t)(n0 + n_l) * NN + m0 + ch * 16);
    dst[0] = *(const uint4*)&tt[n_l][ch * 16];
    dst[1] = *(const uint4*)&tt[n_l][ch * 16 + 8];
}

// ---------------------------------------------------------------------------
// k_mmx: R9-verbatim big GEMM (measured 29.6 µs via R10 double-launch delta).
// parts[ks] = Abf @ zdT^T k-slice. BM=BN=128, BK=64, 256 thr (4 waves 2x2),
// wave tile 64x64 = 2x2 of 32x32x16 frags. Ring-2 LDS, counted vmcnt(8).
// 8-slot XOR chunk swizzle. Split-K=4, bf16 partials row-major.
// ---------------------------------------------------------------------------
__global__ __launch_bounds__(256, 2) void k_mmx(const uint16_t* __restrict__ A,
                                                const uint16_t* __restrict__ Bt,
                                                uint16_t* __restrict__ parts) {
    constexpr int BM = 128, BN = 128, K = NN, SPLITK = 4;
    constexpr int NTC   = FF / BN;        // 4
    constexpr int KSLEN = K / SPLITK;     // 1024
    constexpr int NT    = KSLEN / 64;     // 16
    constexpr int MTX   = (NN / BM) / 8;  // 4

    __shared__ uint16_t As[2][BM * 64];
    __shared__ uint16_t Bs[2][BN * 64];

    const int id   = blockIdx.x;          // 0..511
    const int xcd  = id & 7;
    const int slot = id >> 3;             // 0..63
    const int mt   = xcd * MTX + slot / (NTC * SPLITK);
    const int rem  = slot % (NTC * SPLITK);
    const int nt   = rem % NTC;
    const int ks   = rem / NTC;
    const int m0 = mt * BM;
    const int n0 = nt * BN;
    const int k0 = ks * KSLEN;

    const int tid  = threadIdx.x;
    const int w    = tid >> 6;
    const int lane = tid & 63;
    const int wm = w >> 1, wn = w & 1;

    f32x16 acc[2][2] = {};

    auto STAGE = [&](int t, int buf) {
        const int ktb = k0 + t * 64;
#pragma unroll
        for (int i = 0; i < 4; ++i) {
            const int boff = i * 4096 + tid * 16;
            const int row  = boff >> 7;
            const int q    = (boff >> 4) & 7;
            const int c    = q ^ (row & 7);
            const uint16_t* src = A + (size_t)(m0 + row) * K + ktb + c * 8;
            __builtin_amdgcn_global_load_lds(
                (const __attribute__((address_space(1))) void*)src,
                (__attribute__((address_space(3))) void*)&As[buf][boff >> 1],
                16, 0, 0);
        }
#pragma unroll
        for (int i = 0; i < 4; ++i) {
            const int boff = i * 4096 + tid * 16;
            const int row  = boff >> 7;
            const int q    = (boff >> 4) & 7;
            const int c    = q ^ (row & 7);
            const uint16_t* src = Bt + (size_t)(n0 + row) * K + ktb + c * 8;
            __builtin_amdgcn_global_load_lds(
                (const __attribute__((address_space(1))) void*)src,
                (__attribute__((address_space(3))) void*)&Bs[buf][boff >> 1],
                16, 0, 0);
        }
    };

    auto COMPUTE = [&](int buf) {
#pragma unroll
        for (int kk = 0; kk < 4; ++kk) {
            const int cl = kk * 2 + (lane >> 5);
            bf16x8 af[2], bfr[2];
#pragma unroll
            for (int mf = 0; mf < 2; ++mf) {
                const int r = wm * 64 + mf * 32 + (lane & 31);
                af[mf] = *(const bf16x8*)&As[buf][r * 64 + ((cl ^ (r & 7)) << 3)];
            }
#pragma unroll
            for (int nf = 0; nf < 2; ++nf) {
                const int r = wn * 64 + nf * 32 + (lane & 31);
                bfr[nf] = *(const bf16x8*)&Bs[buf][r * 64 + ((cl ^ (r & 7)) << 3)];
            }
#pragma unroll
            for (int mf = 0; mf < 2; ++mf)
#pragma unroll
                for (int nf = 0; nf < 2; ++nf)
                    acc[mf][nf] = __builtin_amdgcn_mfma_f32_32x32x16_bf16(
                        af[mf], bfr[nf], acc[mf][nf], 0, 0, 0);
        }
    };

    STAGE(0, 0);
    for (int t = 0; t < NT - 1; ++t) {
        STAGE(t + 1, (t + 1) & 1);
        asm volatile("s_waitcnt vmcnt(8)" ::: "memory");
        __builtin_amdgcn_s_barrier();
        COMPUTE(t & 1);
        __builtin_amdgcn_s_barrier();
    }
    asm volatile("s_waitcnt vmcnt(0)" ::: "memory");
    __builtin_amdgcn_s_barrier();
    COMPUTE((NT - 1) & 1);

    uint16_t* dst = parts + (size_t)ks * NN * FF;
    const int rb = m0 + wm * 64 + ((lane >> 5) << 2);
    const int cb = n0 + wn * 64 + (lane & 31);
#pragma unroll
    for (int mf = 0; mf < 2; ++mf)
#pragma unroll
        for (int nf = 0; nf < 2; ++nf) {
            const int gcol = cb + nf * 32;
#pragma unroll
            for (int r = 0; r < 16; ++r) {
                const int grow = rb + mf * 32 + (r & 3) + ((r >> 2) << 3);
                dst[(size_t)grow * FF + gcol] = f2bf(acc[mf][nf][r]);
            }
        }
}

// ---------------------------------------------------------------------------
// k_red: out[i][j] = d[i] * sum_{p=0..3} bf2f(parts[p][i][j]) + b[j]
// ---------------------------------------------------------------------------
__global__ __launch_bounds__(256) void k_red(const uint16_t* __restrict__ parts,
                                             const float* __restrict__ d,
                                             const float* __restrict__ b,
                                             float* __restrict__ out) {
    constexpr size_t STRIDE = (size_t)NN * FF;
    const size_t g   = (size_t)blockIdx.x * 256 + threadIdx.x;
    const int    row = (int)((g * 8) >> 9);
    const int    col = (int)((g * 8) & 511);
    float s[8] = {};
#pragma unroll
    for (int p = 0; p < 4; ++p) {
        ushort4 v0 = *(const ushort4*)(parts + p * STRIDE + g * 8);
        ushort4 v1 = *(const ushort4*)(parts + p * STRIDE + g * 8 + 4);
        s[0] += bf2f(v0.x); s[1] += bf2f(v0.y); s[2] += bf2f(v0.z); s[3] += bf2f(v0.w);
        s[4] += bf2f(v1.x); s[5] += bf2f(v1.y); s[6] += bf2f(v1.z); s[7] += bf2f(v1.w);
    }
    const float di = d[row];
    float4 o0, o1;
    o0.x = s[0] * di + b[col + 0];
    o0.y = s[1] * di + b[col + 1];
    o0.z = s[2] * di + b[col + 2];
    o0.w = s[3] * di + b[col + 3];
    o1.x = s[4] * di + b[col + 4];
    o1.y = s[5] * di + b[col + 5];
    o1.z = s[6] * di + b[col + 6];
    o1.w = s[7] * di + b[col + 7];
    *(float4*)(out + g * 8)     = o0;
    *(float4*)(out + g * 8 + 4) = o1;
}

// ---------------------------------------------------------------------------
extern "C" void kernel_launch(void* const* d_in, const int* in_sizes, int n_in,
                              void* d_out, int out_size, void* d_ws, size_t ws_size,
                              hipStream_t stream) {
    const float* x   = (const float*)d_in[0];   // [4096][512]
    const float* adj = (const float*)d_in[1];   // [4096][4096]
    const float* W   = (const float*)d_in[2];   // [512][512]
    const float* b   = (const float*)d_in[3];   // [512]
    float* out = (float*)d_out;                 // [4096][512] f32

    char* ws = (char*)d_ws;
    float*    d_    = (float*)ws;                                 // 16 KB (pad 64K)
    uint16_t* Abf   = (uint16_t*)(ws + 65536);                    // 32 MB
    uint16_t* zdT   = Abf + (size_t)NN * NN;                      // 4 MB
    uint16_t* xbf   = zdT + (size_t)FF * NN;                      // 4 MB
    uint16_t* Wbf   = xbf + (size_t)NN * FF;                      // 0.5 MB
    uint16_t* parts = Wbf + (size_t)FF * FF;                      // 16 MB (4 x 4MB bf16)

    // one fused preprocessing launch: prep (1024) + xc (2048) + wc (256)
    k_pre<<<3328, 256, 0, stream>>>(adj, x, W, d_, Abf, xbf, Wbf);
    // zdT[n][k] = d_k * (x @ W^T)[k][n]
    k_mmz<<<512, 256, 0, stream>>>(xbf, Wbf, d_, zdT);
    // parts[ks] = Abf @ zdT^T k-slice (R9-verbatim core)
    k_mmx<<<512, 256, 0, stream>>>(Abf, zdT, parts);
    // out = d[i] * sum_ks(parts) + b
    k_red<<<NN * FF / 2048, 256, 0, stream>>>(parts, d_, b, out);
}